// Round 1
// baseline (19155.177 us; speedup 1.0000x reference)
//
#include <hip/hip_runtime.h>
#include <hip/hip_bf16.h>
#include <math.h>

#define S_ 1024
#define B_ 8
#define E_ 768
#define D_ 1024
#define H_ 8
#define DH_ 128
#define F_ 2048
#define L_ 4
#define M_ (S_*B_)   // 8192 tokens

// ---------------- GEMM: C[M,N] = A[M,K] @ W[N,K]^T + bias, opt ReLU ----------
// fp32 baseline: BM=BN=64, BK=16, 256 threads, 4x4 accum per thread.
template<int ACT>
__global__ __launch_bounds__(256) void gemm_bias(
    const float* __restrict__ A, const float* __restrict__ W,
    const float* __restrict__ bias, float* __restrict__ C,
    int M, int N, int K)
{
  __shared__ float As[16][68];   // [k][m], stride 68: 16B-aligned rows, 2-way max conflict
  __shared__ float Ws[16][68];   // [k][n]
  const int bm = blockIdx.y * 64, bn = blockIdx.x * 64;
  const int tid = threadIdx.x;
  const int tm = (tid >> 4) << 2;   // (tid/16)*4
  const int tn = (tid & 15) << 2;   // (tid%16)*4
  float acc[4][4] = {};
  for (int k0 = 0; k0 < K; k0 += 16) {
    #pragma unroll
    for (int i = 0; i < 4; ++i) {
      int r  = (tid >> 4) + i * 16;   // 0..63
      int kk = tid & 15;
      As[kk][r] = A[(size_t)(bm + r) * K + (k0 + kk)];
      Ws[kk][r] = W[(size_t)(bn + r) * K + (k0 + kk)];
    }
    __syncthreads();
    #pragma unroll
    for (int kk = 0; kk < 16; ++kk) {
      float a[4], w[4];
      #pragma unroll
      for (int i = 0; i < 4; ++i) a[i] = As[kk][tm + i];
      #pragma unroll
      for (int j = 0; j < 4; ++j) w[j] = Ws[kk][tn + j];
      #pragma unroll
      for (int i = 0; i < 4; ++i)
        #pragma unroll
        for (int j = 0; j < 4; ++j)
          acc[i][j] = fmaf(a[i], w[j], acc[i][j]);
    }
    __syncthreads();
  }
  #pragma unroll
  for (int i = 0; i < 4; ++i) {
    int row = bm + tm + i;
    #pragma unroll
    for (int j = 0; j < 4; ++j) {
      int col = bn + tn + j;
      float v = acc[i][j] + bias[col];
      if (ACT == 1) v = fmaxf(v, 0.f);
      C[(size_t)row * N + col] = v;
    }
  }
}

// ------------- LayerNorm row kernel: Y = LN(X (+R)) * g + b, opt ReLU --------
// one block (256 threads) per row; D in {512, 1024}
template<bool RESID, bool RELU>
__global__ __launch_bounds__(256) void ln_kernel(
    const float* __restrict__ X, const float* __restrict__ R,
    const float* __restrict__ g, const float* __restrict__ b,
    float* __restrict__ Y, int D)
{
  __shared__ float sbuf[8];
  const int row = blockIdx.x;
  const int tid = threadIdx.x;
  const size_t base = (size_t)row * D;
  const int nt = D >> 8;           // elems per thread (2 or 4)
  float v[4];
  float sum = 0.f, sumsq = 0.f;
  for (int i = 0; i < nt; ++i) {
    int col = tid + (i << 8);
    float t = X[base + col];
    if (RESID) t += R[base + col];
    v[i] = t;
    sum += t;
    sumsq += t * t;
  }
  #pragma unroll
  for (int off = 32; off > 0; off >>= 1) {
    sum   += __shfl_down(sum, off);
    sumsq += __shfl_down(sumsq, off);
  }
  if ((tid & 63) == 0) { sbuf[tid >> 6] = sum; sbuf[4 + (tid >> 6)] = sumsq; }
  __syncthreads();
  sum   = sbuf[0] + sbuf[1] + sbuf[2] + sbuf[3];
  sumsq = sbuf[4] + sbuf[5] + sbuf[6] + sbuf[7];
  const float mean = sum / (float)D;
  const float var  = sumsq / (float)D - mean * mean;
  const float rstd = rsqrtf(var + 1e-5f);
  for (int i = 0; i < nt; ++i) {
    int col = tid + (i << 8);
    float t = (v[i] - mean) * rstd * g[col] + b[col];
    if (RELU) t = fmaxf(t, 0.f);
    Y[base + col] = t;
  }
}

// ---------------- Flash-style attention (fp32 baseline) ----------------------
// QKV: [M][3072] token-major (token = s*B + b); q at col h*128+d, k +1024, v +2048
// O:   [M][1024] pre-projection attention output, col h*128+d
// grid: (32 q-tiles, 64 bh);  block 256.  32 q rows per block, K/V tiles of 32.
__global__ __launch_bounds__(256) void attn_kernel(
    const float* __restrict__ QKV, float* __restrict__ O)
{
  __shared__ float Qs[32][133];   // stride 133 (odd*4+1 vs 32 banks): conflict-free dot reads
  __shared__ float Ks[32][133];
  __shared__ float Vs[32][133];
  __shared__ float Ss[32][33];
  const int qt  = blockIdx.x;      // 0..31
  const int bh  = blockIdx.y;      // 0..63  (= b*H + h)
  const int bb  = bh >> 3;
  const int hh  = bh & 7;
  const int tid = threadIdx.x;

  // load Q tile (32 rows x 128)
  for (int i = 0; i < 16; ++i) {
    int idx = tid + (i << 8);       // 0..4095
    int r = idx >> 7, d = idx & 127;
    int tok = (qt * 32 + r) * B_ + bb;
    Qs[r][d] = QKV[(size_t)tok * 3072 + hh * 128 + d];
  }

  const int qi = tid >> 3;          // q-row owned for softmax/PV: 0..31
  const int d0 = tid & 7;           // dim lane: d = d0 + 8*dd (stride-8 interleave)
  float m = -INFINITY, l = 0.f;
  float Oa[16] = {};
  const float scale = 0.08838834764831845f;  // 1/sqrt(128)

  for (int kt = 0; kt < 32; ++kt) {
    __syncthreads();                // protect Ks/Vs/Ss reuse
    for (int i = 0; i < 16; ++i) {
      int idx = tid + (i << 8);
      int r = idx >> 7, d = idx & 127;
      int tok = (kt * 32 + r) * B_ + bb;
      Ks[r][d] = QKV[(size_t)tok * 3072 + 1024 + hh * 128 + d];
      Vs[r][d] = QKV[(size_t)tok * 3072 + 2048 + hh * 128 + d];
    }
    __syncthreads();
    // scores: 4 per thread (32x32 tile)
    #pragma unroll
    for (int s4 = 0; s4 < 4; ++s4) {
      int id  = tid + (s4 << 8);
      int sqi = id >> 5, stj = id & 31;
      float acc = 0.f;
      #pragma unroll 4
      for (int d = 0; d < 128; ++d)
        acc = fmaf(Qs[sqi][d], Ks[stj][d], acc);
      Ss[sqi][stj] = acc * scale;
    }
    __syncthreads();
    // online softmax update for row qi
    float tmax = -INFINITY;
    #pragma unroll
    for (int tj = 0; tj < 32; ++tj) tmax = fmaxf(tmax, Ss[qi][tj]);
    float mnew  = fmaxf(m, tmax);
    float alpha = __expf(m - mnew);       // first tile: exp(-inf)=0
    #pragma unroll
    for (int d = 0; d < 16; ++d) Oa[d] *= alpha;
    float lsum = 0.f;
    for (int tj = 0; tj < 32; ++tj) {
      float p = __expf(Ss[qi][tj] - mnew);
      lsum += p;
      #pragma unroll
      for (int dd = 0; dd < 16; ++dd)
        Oa[dd] = fmaf(p, Vs[tj][d0 + (dd << 3)], Oa[dd]);
    }
    l = l * alpha + lsum;
    m = mnew;
  }
  const float inv = 1.f / l;
  const int tok = (qt * 32 + qi) * B_ + bb;
  #pragma unroll
  for (int dd = 0; dd < 16; ++dd)
    O[(size_t)tok * 1024 + hh * 128 + d0 + (dd << 3)] = Oa[dd] * inv;
}

// -----------------------------------------------------------------------------
extern "C" void kernel_launch(void* const* d_in, const int* in_sizes, int n_in,
                              void* d_out, int out_size, void* d_ws, size_t ws_size,
                              hipStream_t stream) {
  const float* x        = (const float*)d_in[0];
  const float* enc_w    = (const float*)d_in[1];
  const float* enc_b    = (const float*)d_in[2];
  const float* enc_ln_g = (const float*)d_in[3];
  const float* enc_ln_b = (const float*)d_in[4];
  const float* qkv_w    = (const float*)d_in[5];
  const float* qkv_b    = (const float*)d_in[6];
  const float* out_w    = (const float*)d_in[7];
  const float* out_b    = (const float*)d_in[8];
  const float* ln1_g    = (const float*)d_in[9];
  const float* ln1_b    = (const float*)d_in[10];
  const float* ff1_w    = (const float*)d_in[11];
  const float* ff1_b    = (const float*)d_in[12];
  const float* ff2_w    = (const float*)d_in[13];
  const float* ff2_b    = (const float*)d_in[14];
  const float* ln2_g    = (const float*)d_in[15];
  const float* ln2_b    = (const float*)d_in[16];
  const float* dec_w1   = (const float*)d_in[17];
  const float* dec_b1   = (const float*)d_in[18];
  const float* dec_ln_g = (const float*)d_in[19];
  const float* dec_ln_b = (const float*)d_in[20];
  const float* dec_w2   = (const float*)d_in[21];
  const float* dec_b2   = (const float*)d_in[22];

  float* ws   = (float*)d_ws;
  float* bufH = ws;                                     // M x 1024  (h)
  float* bufA = bufH + (size_t)M_ * 1024;               // M x 3072  (qkv / ff1 / tmp)
  float* bufB = bufA + (size_t)M_ * 3072;               // M x 1024  (attn out / tmp)

  const dim3 blk(256);

  // encoder MLP: h = relu(LN(x @ enc_w^T + enc_b))
  gemm_bias<0><<<dim3(D_/64, M_/64), blk, 0, stream>>>(x, enc_w, enc_b, bufA, M_, D_, E_);
  ln_kernel<false, true><<<M_, blk, 0, stream>>>(bufA, nullptr, enc_ln_g, enc_ln_b, bufH, D_);

  for (int l = 0; l < L_; ++l) {
    // qkv projection
    gemm_bias<0><<<dim3(3*D_/64, M_/64), blk, 0, stream>>>(
        bufH, qkv_w + (size_t)l * 3 * D_ * D_, qkv_b + (size_t)l * 3 * D_, bufA, M_, 3 * D_, D_);
    // attention
    attn_kernel<<<dim3(32, B_ * H_), blk, 0, stream>>>(bufA, bufB);
    // output projection
    gemm_bias<0><<<dim3(D_/64, M_/64), blk, 0, stream>>>(
        bufB, out_w + (size_t)l * D_ * D_, out_b + (size_t)l * D_, bufA, M_, D_, D_);
    // h = LN(h + o)
    ln_kernel<true, false><<<M_, blk, 0, stream>>>(
        bufA, bufH, ln1_g + (size_t)l * D_, ln1_b + (size_t)l * D_, bufH, D_);
    // f = relu(h @ ff1^T + b1) @ ff2^T + b2
    gemm_bias<1><<<dim3(F_/64, M_/64), blk, 0, stream>>>(
        bufH, ff1_w + (size_t)l * F_ * D_, ff1_b + (size_t)l * F_, bufA, M_, F_, D_);
    gemm_bias<0><<<dim3(D_/64, M_/64), blk, 0, stream>>>(
        bufA, ff2_w + (size_t)l * D_ * F_, ff2_b + (size_t)l * D_, bufB, M_, D_, F_);
    // h = LN(h + f)
    ln_kernel<true, false><<<M_, blk, 0, stream>>>(
        bufB, bufH, ln2_g + (size_t)l * D_, ln2_b + (size_t)l * D_, bufH, D_);
  }

  // decoder MLP
  gemm_bias<0><<<dim3((D_/2)/64, M_/64), blk, 0, stream>>>(bufH, dec_w1, dec_b1, bufB, M_, D_/2, D_);
  ln_kernel<false, true><<<M_, blk, 0, stream>>>(bufB, nullptr, dec_ln_g, dec_ln_b, bufB, D_/2);
  gemm_bias<0><<<dim3(E_/64, M_/64), blk, 0, stream>>>(bufB, dec_w2, dec_b2, (float*)d_out, M_, E_, D_/2);
}

// Round 4
// 1524.705 us; speedup vs baseline: 12.5632x; 12.5632x over previous
//
#include <hip/hip_runtime.h>
#include <math.h>

#define S_ 1024
#define B_ 8
#define E_ 768
#define D_ 1024
#define H_ 8
#define F_ 2048
#define L_ 4
#define M_ (S_*B_)   // 8192 tokens

typedef unsigned short u16;
typedef u16 u16x8 __attribute__((ext_vector_type(8)));
typedef u16 u16x4 __attribute__((ext_vector_type(4)));
typedef u16 u16x2 __attribute__((ext_vector_type(2)));
typedef short bf16x8 __attribute__((ext_vector_type(8)));
typedef float f32x4 __attribute__((ext_vector_type(4)));

#define AS1 __attribute__((address_space(1)))
#define AS3 __attribute__((address_space(3)))

__device__ __forceinline__ void gload_lds16(const void* g, void* l) {
  __builtin_amdgcn_global_load_lds((const AS1 void*)g, (AS3 void*)l, 16, 0, 0);
}
__device__ __forceinline__ u16 f2bf(float f) {
  unsigned u = __builtin_bit_cast(unsigned, f);
  return (u16)((u + 0x7fffu + ((u >> 16) & 1u)) >> 16);
}
__device__ __forceinline__ float bf2f(u16 h) {
  unsigned u = ((unsigned)h) << 16;
  return __builtin_bit_cast(float, u);
}

// ---------------- fp32 -> bf16 conversion, 4 tensors per launch -------------
__global__ __launch_bounds__(256) void conv4(
    const float* __restrict__ s0, u16* __restrict__ d0, int n0,
    const float* __restrict__ s1, u16* __restrict__ d1, int n1,
    const float* __restrict__ s2, u16* __restrict__ d2, int n2,
    const float* __restrict__ s3, u16* __restrict__ d3, int n3)
{
  int total = (n0 + n1 + n2 + n3) >> 2;
  for (int i = blockIdx.x * 256 + threadIdx.x; i < total; i += gridDim.x * 256) {
    int e = i << 2;
    const float* s; u16* d; int off;
    if (e < n0)           { s = s0; d = d0; off = e; }
    else if (e < n0+n1)   { s = s1; d = d1; off = e - n0; }
    else if (e < n0+n1+n2){ s = s2; d = d2; off = e - n0 - n1; }
    else                  { s = s3; d = d3; off = e - n0 - n1 - n2; }
    float4 v = *(const float4*)&s[off];
    u16x4 o; o[0]=f2bf(v.x); o[1]=f2bf(v.y); o[2]=f2bf(v.z); o[3]=f2bf(v.w);
    *(u16x4*)&d[off] = o;
  }
}

// ---------------- MFMA GEMM: C[M,N] = A[M,K] @ W[N,K]^T + bias ---------------
// bf16 in, fp32 accum; 128x128 tile, BK=32, 256 thr (4 waves 2x2), 4x4 frags.
template<int ACT, int OUTBF>
__global__ __launch_bounds__(256) void gemm_mfma(
    const u16* __restrict__ A, const u16* __restrict__ W,
    const float* __restrict__ bias, void* __restrict__ Cout,
    int M, int N, int K)
{
  __shared__ u16 As[128*32];
  __shared__ u16 Bs[128*32];
  const int bm = blockIdx.y * 128, bn = blockIdx.x * 128;
  const int tid = threadIdx.x;
  const int w = tid >> 6, l = tid & 63;
  const int l15 = l & 15, lg = l >> 4;
  const int wr = w >> 1, wc = w & 1;
  f32x4 acc[4][4] = {};

  for (int k0 = 0; k0 < K; k0 += 32) {
    __syncthreads();
    #pragma unroll
    for (int j = 0; j < 2; ++j) {
      int e = (w*2 + j) * 512 + l * 8;
      int row = e >> 5, ko = (l & 3) * 8;
      gload_lds16(A + (size_t)(bm + row) * K + k0 + ko, &As[(w*2 + j) * 512]);
      gload_lds16(W + (size_t)(bn + row) * K + k0 + ko, &Bs[(w*2 + j) * 512]);
    }
    __syncthreads();
    bf16x8 af[4], bf_[4];
    #pragma unroll
    for (int mi = 0; mi < 4; ++mi) {
      int row = wr*64 + mi*16 + l15;
      af[mi] = *(const bf16x8*)&As[row*32 + lg*8];
    }
    #pragma unroll
    for (int ni = 0; ni < 4; ++ni) {
      int row = wc*64 + ni*16 + l15;
      bf_[ni] = *(const bf16x8*)&Bs[row*32 + lg*8];
    }
    #pragma unroll
    for (int mi = 0; mi < 4; ++mi)
      #pragma unroll
      for (int ni = 0; ni < 4; ++ni)
        acc[mi][ni] = __builtin_amdgcn_mfma_f32_16x16x32_bf16(af[mi], bf_[ni], acc[mi][ni], 0, 0, 0);
  }

  u16* Cb = (u16*)Cout; float* Cf = (float*)Cout;
  #pragma unroll
  for (int ni = 0; ni < 4; ++ni) {
    int col = bn + wc*64 + ni*16 + l15;
    float bv = bias[col];
    #pragma unroll
    for (int mi = 0; mi < 4; ++mi) {
      #pragma unroll
      for (int rr = 0; rr < 4; ++rr) {
        int row = bm + wr*64 + mi*16 + lg*4 + rr;
        float v = acc[mi][ni][rr] + bv;
        if (ACT) v = fmaxf(v, 0.f);
        if (OUTBF) Cb[(size_t)row * N + col] = f2bf(v);
        else       Cf[(size_t)row * N + col] = v;
      }
    }
  }
}

// ------------- LayerNorm: Y = LN(X (+R)) * g + b, opt ReLU; bf16 io ----------
template<int NV, bool RESID, bool RELU>
__global__ __launch_bounds__(256) void ln_bf16(
    const u16* __restrict__ X, const u16* __restrict__ R,
    const float* __restrict__ g, const float* __restrict__ b,
    u16* __restrict__ Y)
{
  constexpr int D = NV * 256;
  __shared__ float sbuf[8];
  const int tid = threadIdx.x;
  const size_t base = (size_t)blockIdx.x * D + tid * NV;
  float v[NV];
  if constexpr (NV == 4) {
    u16x4 xv = *(const u16x4*)&X[base];
    #pragma unroll
    for (int i = 0; i < 4; ++i) v[i] = bf2f(xv[i]);
    if (RESID) {
      u16x4 rv = *(const u16x4*)&R[base];
      #pragma unroll
      for (int i = 0; i < 4; ++i) v[i] += bf2f(rv[i]);
    }
  } else {
    u16x2 xv = *(const u16x2*)&X[base];
    #pragma unroll
    for (int i = 0; i < 2; ++i) v[i] = bf2f(xv[i]);
    if (RESID) {
      u16x2 rv = *(const u16x2*)&R[base];
      #pragma unroll
      for (int i = 0; i < 2; ++i) v[i] += bf2f(rv[i]);
    }
  }
  float sum = 0.f, sq = 0.f;
  #pragma unroll
  for (int i = 0; i < NV; ++i) { sum += v[i]; sq += v[i]*v[i]; }
  #pragma unroll
  for (int off = 32; off > 0; off >>= 1) {
    sum += __shfl_down(sum, off);
    sq  += __shfl_down(sq, off);
  }
  if ((tid & 63) == 0) { sbuf[tid >> 6] = sum; sbuf[4 + (tid >> 6)] = sq; }
  __syncthreads();
  sum = sbuf[0] + sbuf[1] + sbuf[2] + sbuf[3];
  sq  = sbuf[4] + sbuf[5] + sbuf[6] + sbuf[7];
  const float mean = sum / (float)D;
  const float rstd = rsqrtf(sq / (float)D - mean*mean + 1e-5f);
  const int c0 = tid * NV;
  if constexpr (NV == 4) {
    u16x4 o;
    #pragma unroll
    for (int i = 0; i < 4; ++i) {
      float t = (v[i] - mean) * rstd * g[c0+i] + b[c0+i];
      if (RELU) t = fmaxf(t, 0.f);
      o[i] = f2bf(t);
    }
    *(u16x4*)&Y[base] = o;
  } else {
    u16x2 o;
    #pragma unroll
    for (int i = 0; i < 2; ++i) {
      float t = (v[i] - mean) * rstd * g[c0+i] + b[c0+i];
      if (RELU) t = fmaxf(t, 0.f);
      o[i] = f2bf(t);
    }
    *(u16x2*)&Y[base] = o;
  }
}

// ---------- V transpose: QKV V-part -> Vt[bh][d][s]  (linear, no swizzle) ----
// LDS tile stride 132 u16 (row width 128 + pad 4).
__global__ __launch_bounds__(256) void vtrans(
    const u16* __restrict__ QKV, u16* __restrict__ Vt)
{
  __shared__ u16 Ls[32*132];
  const int st = blockIdx.x, bh = blockIdx.y;
  const int bb = bh >> 3, hh = bh & 7;
  const int t = threadIdx.x;
  #pragma unroll
  for (int i = 0; i < 2; ++i) {
    int e = i*256 + t;
    int s = e >> 4, d0 = (e & 15) * 8;
    u16x8 v = *(const u16x8*)&QKV[(size_t)((st*32 + s)*8 + bb)*3072 + 2048 + hh*128 + d0];
    #pragma unroll
    for (int j = 0; j < 4; ++j) {
      u16x2 p; p[0] = v[2*j]; p[1] = v[2*j+1];
      *(u16x2*)&Ls[s*132 + d0 + 2*j] = p;
    }
  }
  __syncthreads();
  #pragma unroll
  for (int i = 0; i < 2; ++i) {
    int e = i*256 + t;
    int d = e >> 2, s0 = (e & 3) * 8;
    u16x8 v;
    #pragma unroll
    for (int j = 0; j < 8; ++j) v[j] = Ls[(s0+j)*132 + d];
    *(u16x8*)&Vt[(size_t)bh*131072 + (size_t)d*1024 + st*32 + s0] = v;
  }
}

// ---------------- Flash attention, bf16 MFMA --------------------------------
// grid (16 q-tiles, 64 bh), block 256 (4 waves x 16 q-rows). KV tiles of 32.
__global__ __launch_bounds__(256) void attn_mfma(
    const u16* __restrict__ QKV, const u16* __restrict__ Vt,
    u16* __restrict__ AO)
{
  __shared__ u16 Qs[64*128];
  __shared__ u16 Ks[32*128];
  __shared__ u16 Vs[128*32];
  __shared__ u16 Pl[4][16*40];
  const int qt = blockIdx.x, bh = blockIdx.y;
  const int bb = bh >> 3, hh = bh & 7;
  const int tid = threadIdx.x, w = tid >> 6, l = tid & 63;
  const int l15 = l & 15, lg = l >> 4;

  // stage Q (64x128) with source-side XOR swizzle (row stride 128: 7-bit ok)
  #pragma unroll
  for (int i = 0; i < 4; ++i) {
    int e = (w*4 + i) * 512 + l * 8;
    int row = e >> 7, d0 = e & 127;
    int dsw = d0 ^ ((row & 7) << 3);
    gload_lds16(QKV + (size_t)((qt*64 + row)*8 + bb)*3072 + hh*128 + dsw,
                &Qs[(w*4 + i) * 512]);
  }

  f32x4 of[8] = {};
  float mreg[4], lreg[4];
  #pragma unroll
  for (int r = 0; r < 4; ++r) { mreg[r] = -INFINITY; lreg[r] = 0.f; }
  const float scale = 0.08838834764831845f;  // 1/sqrt(128)

  for (int kt = 0; kt < 32; ++kt) {
    __syncthreads();
    #pragma unroll
    for (int i = 0; i < 2; ++i) {
      int e = (w*2 + i) * 512 + l * 8;
      int krow = e >> 7, d0 = e & 127;
      int dsw = d0 ^ ((krow & 7) << 3);
      gload_lds16(QKV + (size_t)((kt*32 + krow)*8 + bb)*3072 + 1024 + hh*128 + dsw,
                  &Ks[(w*2 + i) * 512]);
      int vd = e >> 5, vk = (l & 3) * 8;
      gload_lds16(Vt + (size_t)bh*131072 + (size_t)vd*1024 + kt*32 + vk,
                  &Vs[(w*2 + i) * 512]);
    }
    __syncthreads();

    // S = Q K^T (wave's 16 q-rows x 32 keys)
    f32x4 s0 = {}, s1 = {};
    #pragma unroll
    for (int kc = 0; kc < 4; ++kc) {
      int qrow = w*16 + l15;
      int dd = kc*32 + lg*8;
      bf16x8 aq = *(const bf16x8*)&Qs[qrow*128 + (dd ^ ((qrow & 7) << 3))];
      bf16x8 b0 = *(const bf16x8*)&Ks[l15*128 + (dd ^ ((l15 & 7) << 3))];
      int kr1 = 16 + l15;
      bf16x8 b1 = *(const bf16x8*)&Ks[kr1*128 + (dd ^ ((kr1 & 7) << 3))];
      s0 = __builtin_amdgcn_mfma_f32_16x16x32_bf16(aq, b0, s0, 0, 0, 0);
      s1 = __builtin_amdgcn_mfma_f32_16x16x32_bf16(aq, b1, s1, 0, 0, 0);
    }
    // online softmax; lane holds rows lg*4+r, key l15 (f0) / 16+l15 (f1)
    #pragma unroll
    for (int r = 0; r < 4; ++r) {
      float a0 = s0[r] * scale, a1 = s1[r] * scale;
      float t = fmaxf(a0, a1);
      t = fmaxf(t, __shfl_xor(t, 1));
      t = fmaxf(t, __shfl_xor(t, 2));
      t = fmaxf(t, __shfl_xor(t, 4));
      t = fmaxf(t, __shfl_xor(t, 8));
      float mn = fmaxf(mreg[r], t);
      float al = __expf(mreg[r] - mn);
      mreg[r] = mn;
      float p0 = __expf(a0 - mn), p1 = __expf(a1 - mn);
      float ls = p0 + p1;
      ls += __shfl_xor(ls, 1);
      ls += __shfl_xor(ls, 2);
      ls += __shfl_xor(ls, 4);
      ls += __shfl_xor(ls, 8);
      lreg[r] = lreg[r] * al + ls;
      int prow = lg*4 + r;
      Pl[w][prow*40 + l15]      = f2bf(p0);
      Pl[w][prow*40 + 16 + l15] = f2bf(p1);
      #pragma unroll
      for (int ni = 0; ni < 8; ++ni) of[ni][r] *= al;
    }
    // O += P V  (per-wave private Pl; same-wave LDS ops are ordered by hw)
    bf16x8 pa = *(const bf16x8*)&Pl[w][l15*40 + lg*8];
    #pragma unroll
    for (int ni = 0; ni < 8; ++ni) {
      int n = ni*16 + l15;
      bf16x8 vb = *(const bf16x8*)&Vs[n*32 + lg*8];
      of[ni] = __builtin_amdgcn_mfma_f32_16x16x32_bf16(pa, vb, of[ni], 0, 0, 0);
    }
  }

  #pragma unroll
  for (int r = 0; r < 4; ++r) {
    float inv = 1.f / lreg[r];
    int q = qt*64 + w*16 + lg*4 + r;
    size_t base = (size_t)(q*8 + bb) * 1024 + hh*128;
    #pragma unroll
    for (int ni = 0; ni < 8; ++ni)
      AO[base + ni*16 + l15] = f2bf(of[ni][r] * inv);
  }
}

// ------------------------- workspace layout (u16 units) ----------------------
#define O_WENC  0ull
#define O_WDEC1 786432ull
#define O_WDEC2 1310720ull
#define O_WLQ   1703936ull
#define O_WLO   4849664ull
#define O_WLF1  5898240ull
#define O_WLF2  7995392ull
#define O_R     10092544ull            // 25165824 elems: QKV | [Y(8.39M) G(16.78M)]
#define O_H     35258368ull
#define O_AO    43646976ull
#define O_VT    52035584ull

extern "C" void kernel_launch(void* const* d_in, const int* in_sizes, int n_in,
                              void* d_out, int out_size, void* d_ws, size_t ws_size,
                              hipStream_t stream) {
  (void)in_sizes; (void)n_in; (void)out_size; (void)ws_size;
  const float* x        = (const float*)d_in[0];
  const float* enc_w    = (const float*)d_in[1];
  const float* enc_b    = (const float*)d_in[2];
  const float* enc_ln_g = (const float*)d_in[3];
  const float* enc_ln_b = (const float*)d_in[4];
  const float* qkv_w    = (const float*)d_in[5];
  const float* qkv_b    = (const float*)d_in[6];
  const float* out_w    = (const float*)d_in[7];
  const float* out_b    = (const float*)d_in[8];
  const float* ln1_g    = (const float*)d_in[9];
  const float* ln1_b    = (const float*)d_in[10];
  const float* ff1_w    = (const float*)d_in[11];
  const float* ff1_b    = (const float*)d_in[12];
  const float* ff2_w    = (const float*)d_in[13];
  const float* ff2_b    = (const float*)d_in[14];
  const float* ln2_g    = (const float*)d_in[15];
  const float* ln2_b    = (const float*)d_in[16];
  const float* dec_w1   = (const float*)d_in[17];
  const float* dec_b1   = (const float*)d_in[18];
  const float* dec_ln_g = (const float*)d_in[19];
  const float* dec_ln_b = (const float*)d_in[20];
  const float* dec_w2   = (const float*)d_in[21];
  const float* dec_b2   = (const float*)d_in[22];

  u16* ws16 = (u16*)d_ws;
  u16* wenc  = ws16 + O_WENC;
  u16* wdec1 = ws16 + O_WDEC1;
  u16* wdec2 = ws16 + O_WDEC2;
  u16* wlq   = ws16 + O_WLQ;
  u16* wlo   = ws16 + O_WLO;
  u16* wlf1  = ws16 + O_WLF1;
  u16* wlf2  = ws16 + O_WLF2;
  u16* qkv   = ws16 + O_R;                 // 8192 x 3072
  u16* bufY  = ws16 + O_R;                 // 8192 x 1024 (after attn)
  u16* bufG  = ws16 + O_R + 8388608ull;    // 8192 x 2048 (FF) / xb / dech
  u16* xb    = bufG;
  u16* dech  = bufG;
  u16* h     = ws16 + O_H;
  u16* ao    = ws16 + O_AO;
  u16* vt    = ws16 + O_VT;

  const dim3 blk(256);

  // weights/input -> bf16 (encoder + decoder)
  conv4<<<1024, blk, 0, stream>>>(x, xb, 8192*768,
                                  enc_w, wenc, 1024*768,
                                  dec_w1, wdec1, 512*1024,
                                  dec_w2, wdec2, 768*512);
  // encoder MLP
  gemm_mfma<0,1><<<dim3(8,64), blk, 0, stream>>>(xb, wenc, enc_b, bufY, M_, 1024, 768);
  ln_bf16<4,false,true><<<M_, blk, 0, stream>>>(bufY, nullptr, enc_ln_g, enc_ln_b, h);

  for (int l = 0; l < L_; ++l) {
    conv4<<<1024, blk, 0, stream>>>(qkv_w + (size_t)l*3145728, wlq, 3145728,
                                    out_w + (size_t)l*1048576, wlo, 1048576,
                                    ff1_w + (size_t)l*2097152, wlf1, 2097152,
                                    ff2_w + (size_t)l*2097152, wlf2, 2097152);
    gemm_mfma<0,1><<<dim3(24,64), blk, 0, stream>>>(h, wlq, qkv_b + (size_t)l*3072, qkv, M_, 3072, 1024);
    vtrans<<<dim3(32,64), blk, 0, stream>>>(qkv, vt);
    attn_mfma<<<dim3(16,64), blk, 0, stream>>>(qkv, vt, ao);
    gemm_mfma<0,1><<<dim3(8,64), blk, 0, stream>>>(ao, wlo, out_b + (size_t)l*1024, bufY, M_, 1024, 1024);
    ln_bf16<4,true,false><<<M_, blk, 0, stream>>>(bufY, h, ln1_g + (size_t)l*1024, ln1_b + (size_t)l*1024, h);
    gemm_mfma<1,1><<<dim3(16,64), blk, 0, stream>>>(h, wlf1, ff1_b + (size_t)l*2048, bufG, M_, 2048, 1024);
    gemm_mfma<0,1><<<dim3(8,64), blk, 0, stream>>>(bufG, wlf2, ff2_b + (size_t)l*1024, bufY, M_, 1024, 2048);
    ln_bf16<4,true,false><<<M_, blk, 0, stream>>>(bufY, h, ln2_g + (size_t)l*1024, ln2_b + (size_t)l*1024, h);
  }

  // decoder MLP
  gemm_mfma<0,1><<<dim3(4,64), blk, 0, stream>>>(h, wdec1, dec_b1, bufY, M_, 512, 1024);
  ln_bf16<2,false,true><<<M_, blk, 0, stream>>>(bufY, nullptr, dec_ln_g, dec_ln_b, dech);
  gemm_mfma<0,0><<<dim3(6,64), blk, 0, stream>>>(dech, wdec2, dec_b2, d_out, M_, 768, 512);
}